// Round 4
// baseline (390.272 us; speedup 1.0000x reference)
//
#include <hip/hip_runtime.h>

#define N_NODES 20000
#define N_EDGES 640000
#define E_TOT   (N_EDGES + N_NODES)   /* 660000: edges + self loops */
#define IN_DIM  128
#define HIDDEN  256
#define OUT_DIM 64
#define LOG2E 1.4426950408889634f

typedef __attribute__((ext_vector_type(2))) float f32x2;

__device__ __forceinline__ unsigned short f2bf(float f) {
    union { float f; unsigned int i; } x; x.f = f;
    unsigned int u = x.i;
    return (unsigned short)((u + 0x7fffu + ((u >> 16) & 1u)) >> 16);  // RTNE
}
__device__ __forceinline__ f32x2 up2(unsigned int p) {   // 2 packed bf16 -> 2 fp32
    f32x2 r;
    r.x = __uint_as_float(p << 16);
    r.y = __uint_as_float(p & 0xffff0000u);
    return r;
}
__device__ __forceinline__ unsigned int pk2(float a, float b) {
    return (unsigned int)f2bf(a) | ((unsigned int)f2bf(b) << 16);
}

// ---------------- CSR build (by dst) ----------------

__global__ void zero_cnt_kernel(int* __restrict__ cnt) {
    int i = blockIdx.x * blockDim.x + threadIdx.x;
    if (i < N_NODES) cnt[i] = 0;
}

__global__ void count_kernel(const int* __restrict__ edge_dst, int* __restrict__ cnt) {
    int i = blockIdx.x * blockDim.x + threadIdx.x;
    if (i >= E_TOT) return;
    int d = (i < N_EDGES) ? edge_dst[i] : (i - N_EDGES);   // implicit self-loop tail
    atomicAdd(&cnt[d], 1);
}

__global__ __launch_bounds__(1024) void scan_kernel(int* __restrict__ cnt, int* __restrict__ indptr) {
    const int T = 1024;
    const int C = (N_NODES + T - 1) / T;   // 20 per thread
    __shared__ int sums[T];
    int t = threadIdx.x;
    int base = t * C;
    int local[C];
    int s = 0;
#pragma unroll
    for (int i = 0; i < C; i++) {
        int idx = base + i;
        int v = (idx < N_NODES) ? cnt[idx] : 0;
        local[i] = s;
        s += v;
    }
    sums[t] = s;
    __syncthreads();
    for (int off = 1; off < T; off <<= 1) {
        int v = (t >= off) ? sums[t - off] : 0;
        __syncthreads();
        sums[t] += v;
        __syncthreads();
    }
    int prefix = (t == 0) ? 0 : sums[t - 1];
#pragma unroll
    for (int i = 0; i < C; i++) {
        int idx = base + i;
        if (idx < N_NODES) {
            indptr[idx] = prefix + local[i];
            cnt[idx] = 0;                   // cursor for scatter
        }
    }
    if (t == T - 1) indptr[N_NODES] = prefix + s;   // == E_TOT
}

__global__ void scatter_kernel(const int* __restrict__ edge_src, const int* __restrict__ edge_dst,
                               const int* __restrict__ indptr, int* __restrict__ cnt,
                               int* __restrict__ ssrc) {
    int i = blockIdx.x * blockDim.x + threadIdx.x;
    if (i >= E_TOT) return;
    int d, s;
    if (i < N_EDGES) { d = edge_dst[i]; s = edge_src[i]; }
    else             { d = i - N_EDGES; s = d; }
    int pos = indptr[d] + atomicAdd(&cnt[d], 1);
    ssrc[pos] = s;
}

// ---------------- fp32 tiled GEMM + bias + optional relu ----------------

__global__ __launch_bounds__(256) void gemm_bias_act(const float* __restrict__ A,
                                                     const float* __restrict__ B,
                                                     const float* __restrict__ bias,
                                                     float* __restrict__ C,
                                                     int M, int Nn, int K, int relu) {
    __shared__ float As[16][65];
    __shared__ float Bs[16][65];
    int tid = threadIdx.x;
    int tx = tid & 15, ty = tid >> 4;
    int row0 = blockIdx.x * 64, col0 = blockIdx.y * 64;
    float acc[4][4] = {};
    for (int k0 = 0; k0 < K; k0 += 16) {
        {
            int r_ = tid >> 2;
            int kq = (tid & 3) * 4;
            int gr = row0 + r_;
            float4 a4 = make_float4(0.f, 0.f, 0.f, 0.f);
            if (gr < M) a4 = *(const float4*)&A[(long)gr * K + k0 + kq];
            As[kq + 0][r_] = a4.x; As[kq + 1][r_] = a4.y;
            As[kq + 2][r_] = a4.z; As[kq + 3][r_] = a4.w;
        }
        {
            int kr = tid >> 4;
            int cq = (tid & 15) * 4;
            float4 b4 = *(const float4*)&B[(long)(k0 + kr) * Nn + col0 + cq];
            Bs[kr][cq + 0] = b4.x; Bs[kr][cq + 1] = b4.y;
            Bs[kr][cq + 2] = b4.z; Bs[kr][cq + 3] = b4.w;
        }
        __syncthreads();
#pragma unroll
        for (int kk = 0; kk < 16; kk++) {
            float a[4], b[4];
#pragma unroll
            for (int i = 0; i < 4; i++) a[i] = As[kk][ty * 4 + i];
#pragma unroll
            for (int j = 0; j < 4; j++) b[j] = Bs[kk][tx * 4 + j];
#pragma unroll
            for (int i = 0; i < 4; i++)
#pragma unroll
                for (int j = 0; j < 4; j++) acc[i][j] += a[i] * b[j];
        }
        __syncthreads();
    }
#pragma unroll
    for (int i = 0; i < 4; i++) {
        int gr = row0 + ty * 4 + i;
        if (gr >= M) continue;
#pragma unroll
        for (int j = 0; j < 4; j++) {
            int gc = col0 + tx * 4 + j;
            float v = acc[i][j] + bias[gc];
            if (relu) v = fmaxf(v, 0.f);
            C[(long)gr * Nn + gc] = v;
        }
    }
}

// ---------------- initial normalize: fp32 h -> bf16 hn + fp32 r ----------------

__global__ __launch_bounds__(256) void normalize0_kernel(const float* __restrict__ h,
                                                         unsigned short* __restrict__ hnb,
                                                         float* __restrict__ r) {
    int i = blockIdx.x;
    int c = threadIdx.x;
    float v = h[(long)i * HIDDEN + c];
    float ss = v * v;
#pragma unroll
    for (int off = 32; off; off >>= 1) ss += __shfl_xor(ss, off);
    __shared__ float wsum[4];
    int wid = c >> 6, lane = c & 63;
    if (lane == 0) wsum[wid] = ss;
    __syncthreads();
    float tot = wsum[0] + wsum[1] + wsum[2] + wsum[3];
    float rr = sqrtf(tot + 1e-12f);
    hnb[(long)i * HIDDEN + c] = f2bf(v / rr);
    if (c == 0) r[i] = rr;
}

// ---------------- fused AGNN layer ----------------
// One node per 32-lane half-wave (2 nodes/wave, 8 ch/lane = one uint4).
// 10000 waves -> exceeds the 8192 resident-wave slots (R2 had 5000 -> 34% occ).
// Softmax without max-subtraction: logits are cosines in [-1,1] (exp in
// [0.37,2.7]); hd pre-scaled by log2e so weight = native v_exp_f32.
// 3-stage pipeline: index for e+3 and row for e+2 issued at iteration e.

__global__ __launch_bounds__(256) void agnn_kernel(const unsigned short* __restrict__ hnb,
                                                   const float* __restrict__ rin,
                                                   const int* __restrict__ indptr,
                                                   const int* __restrict__ ssrc,
                                                   unsigned short* __restrict__ hnout,
                                                   float* __restrict__ rout,
                                                   float* __restrict__ hout,
                                                   int write_hn) {
    int wid = threadIdx.x >> 6;           // wave in block (0..3)
    int g   = (threadIdx.x >> 5) & 1;     // half-wave group
    int gl  = threadIdx.x & 31;           // lane in group
    int node = blockIdx.x * 8 + wid * 2 + g;   // grid exact: 2500*8 = 20000

    const uint4* tab4 = (const uint4*)hnb;     // one uint4 = 8 bf16; row = 32 uint4
    long nb = (long)node * 32 + gl;
    uint4 hv = tab4[nb];
    f32x2 hd2[4];
    hd2[0] = up2(hv.x) * LOG2E;
    hd2[1] = up2(hv.y) * LOG2E;
    hd2[2] = up2(hv.z) * LOG2E;
    hd2[3] = up2(hv.w) * LOG2E;

    int beg = indptr[node], end = indptr[node + 1];
    int n = end - beg;                 // >= 1 (self loop)
    int last = end - 1;
    int nmax = max(n, __shfl_xor(n, 32));   // uniform loop bound across the wave

    f32x2 acc[4];
#pragma unroll
    for (int p = 0; p < 4; p++) acc[p] = (f32x2)0.f;
    float z = 0.f;

    // pipeline prologue: rows for e0,e1 in flight; index for e2 in flight
    int e1 = (1 > last - beg) ? last : beg + 1;
    int e2 = (2 > last - beg) ? last : beg + 2;
    int s0 = ssrc[beg];
    int s1 = ssrc[e1];
    uint4 v0 = tab4[(long)s0 * 32 + gl];
    float r0 = rin[s0];
    uint4 v1 = tab4[(long)s1 * 32 + gl];
    float r1 = rin[s1];
    int s2 = ssrc[e2];

    for (int i = 0; i < nmax; i++) {
        uint4 cv = v0;
        float cr = r0;
        v0 = v1; r0 = r1;
        // row load for e+2 (index s2 loaded one iteration ago)
        v1 = tab4[(long)s2 * 32 + gl];
        r1 = rin[s2];
        // index load for e+3 (used next iteration)
        int e3 = beg + i + 3;
        e3 = (e3 > last) ? last : e3;
        s2 = ssrc[e3];

        f32x2 cf[4];
        cf[0] = up2(cv.x); cf[1] = up2(cv.y); cf[2] = up2(cv.z); cf[3] = up2(cv.w);
        f32x2 d2a = cf[0] * hd2[0];
        f32x2 d2b = cf[1] * hd2[1];
        d2a += cf[2] * hd2[2];
        d2b += cf[3] * hd2[3];
        f32x2 d2 = d2a + d2b;
        float d = d2.x + d2.y;
        d += __shfl_xor(d, 1);
        d += __shfl_xor(d, 2);
        d += __shfl_xor(d, 4);
        d += __shfl_xor(d, 8);
        d += __shfl_xor(d, 16);
        float w = (i < n) ? exp2f(d) : 0.f;   // masked tail for the shorter group
        z += w;
        float wr = w * cr;
#pragma unroll
        for (int p = 0; p < 4; p++) acc[p] += cf[p] * wr;
    }

    float inv = 1.f / z;
    f32x2 o[4];
#pragma unroll
    for (int p = 0; p < 4; p++) {
        f32x2 t = acc[p] * inv;
        t.x = fmaxf(t.x, 0.f);
        t.y = fmaxf(t.y, 0.f);
        o[p] = t;
    }

    if (write_hn) {
        float ss = 0.f;
#pragma unroll
        for (int p = 0; p < 4; p++) ss += o[p].x * o[p].x + o[p].y * o[p].y;
        ss += __shfl_xor(ss, 1);
        ss += __shfl_xor(ss, 2);
        ss += __shfl_xor(ss, 4);
        ss += __shfl_xor(ss, 8);
        ss += __shfl_xor(ss, 16);
        float rr = sqrtf(ss + 1e-12f);
        float ir = 1.f / rr;
        uint4 ov;
        ov.x = pk2(o[0].x * ir, o[0].y * ir);
        ov.y = pk2(o[1].x * ir, o[1].y * ir);
        ov.z = pk2(o[2].x * ir, o[2].y * ir);
        ov.w = pk2(o[3].x * ir, o[3].y * ir);
        ((uint4*)hnout)[nb] = ov;
        if (gl == 0) rout[node] = rr;
    } else {
        float4* ho = (float4*)(hout + (long)node * HIDDEN + gl * 8);
        ho[0] = make_float4(o[0].x, o[0].y, o[1].x, o[1].y);
        ho[1] = make_float4(o[2].x, o[2].y, o[3].x, o[3].y);
    }
}

// ---------------- launch ----------------

extern "C" void kernel_launch(void* const* d_in, const int* in_sizes, int n_in,
                              void* d_out, int out_size, void* d_ws, size_t ws_size,
                              hipStream_t stream) {
    const float* x  = (const float*)d_in[0];
    const int* esrc = (const int*)d_in[1];
    const int* edst = (const int*)d_in[2];
    const float* W1 = (const float*)d_in[3];
    const float* b1 = (const float*)d_in[4];
    const float* W2 = (const float*)d_in[5];
    const float* b2 = (const float*)d_in[6];
    float* out = (float*)d_out;

    char* ws = (char*)d_ws;
    float*          h0     = (float*)(ws);                          // 20,480,000 B
    unsigned short* hnA    = (unsigned short*)(ws + 20480000);      // 10,240,000 B
    unsigned short* hnB    = (unsigned short*)(ws + 30720000);      // 10,240,000 B
    float*          rA     = (float*)(ws + 40960000);               // 80,000 B
    float*          rB     = (float*)(ws + 41040000);               // 80,000 B
    int*            indptr = (int*)  (ws + 41120000);               // 80,004 B (pad)
    int*            cnt    = (int*)  (ws + 41200256);               // 80,000 B
    int*            ssrc   = (int*)  (ws + 41280256);               // 2,640,000 B

    zero_cnt_kernel<<<(N_NODES + 255) / 256, 256, 0, stream>>>(cnt);
    count_kernel<<<(E_TOT + 255) / 256, 256, 0, stream>>>(edst, cnt);
    scan_kernel<<<1, 1024, 0, stream>>>(cnt, indptr);
    scatter_kernel<<<(E_TOT + 255) / 256, 256, 0, stream>>>(esrc, edst, indptr, cnt, ssrc);

    dim3 g1((N_NODES + 63) / 64, HIDDEN / 64);
    gemm_bias_act<<<g1, 256, 0, stream>>>(x, W1, b1, h0, N_NODES, HIDDEN, IN_DIM, 1);

    normalize0_kernel<<<N_NODES, 256, 0, stream>>>(h0, hnA, rA);

    int nblk = N_NODES / 8;   // 2500, exact
    // L0: A -> B, L1: B -> A, L2: A -> B, L3: B -> h0 (fp32)
    agnn_kernel<<<nblk, 256, 0, stream>>>(hnA, rA, indptr, ssrc, hnB, rB, h0, 1);
    agnn_kernel<<<nblk, 256, 0, stream>>>(hnB, rB, indptr, ssrc, hnA, rA, h0, 1);
    agnn_kernel<<<nblk, 256, 0, stream>>>(hnA, rA, indptr, ssrc, hnB, rB, h0, 1);
    agnn_kernel<<<nblk, 256, 0, stream>>>(hnB, rB, indptr, ssrc, hnA, rA, h0, 0);

    dim3 g2((N_NODES + 63) / 64, OUT_DIM / 64);
    gemm_bias_act<<<g2, 256, 0, stream>>>(h0, W2, b2, out, N_NODES, OUT_DIM, HIDDEN, 0);
}